// Round 6
// baseline (419.706 us; speedup 1.0000x reference)
//
#include <hip/hip_runtime.h>

// ---------------------------------------------------------------------------
// GGNN message passing, MI355X/gfx950.  Round 6: fuse the CSR gather into the
// message GEMM (S intermediate eliminated: -51.2MB write -51.2MB read), GRU
// GEMM reads X once and takes h from the staged LDS tile (-25.6MB), prep
// kernels merged (14 -> 8 dispatches).
//
// Dataflow:
//   CSR segmented by (dst, type): rowptr4[n*4+t]  (hist4 -> scan -> fill4)
//   spmm_gemm: per K-chunk t, waves gather type-t neighbor hbf rows straight
//     into the LDS A-tile, then MFMA vs Wcat chunk t; bias from segment
//     lengths; aggbf written via LDS restage (coalesced).
//   gemm_gru: C' = Wg[512x256] @ [aggbf|hbf]^T, full gate dim per block,
//     64-node tiles; gate rows 4j+{r,z,i_n,h_n} land in one lane's 4 acc
//     regs; fused GRU nonlinearity; h taken from the hbf LDS tile; out via
//     fp32 LDS tile, coalesced float4 stores.
// ---------------------------------------------------------------------------

typedef __attribute__((ext_vector_type(8))) short short8;
typedef __attribute__((ext_vector_type(4))) float floatx4;

#define HID 128
#define NTY 4

__device__ __forceinline__ unsigned short f2bf(float f) {
    unsigned int u = __float_as_uint(f);
    unsigned int r = (u + 0x7fffu + ((u >> 16) & 1u)) >> 16;  // RNE
    return (unsigned short)r;
}
__device__ __forceinline__ float bf2f(unsigned int lo16) {
    return __uint_as_float(lo16 << 16);
}

// ---- prep: cvt_h | pack_wcat | pack_wgru | zero deg4, one kernel ----------

__global__ void prep_kernel(const float* __restrict__ h, unsigned short* __restrict__ hbf,
                            const float* __restrict__ W, unsigned short* __restrict__ Wc,
                            const float* __restrict__ w_ih, const float* __restrict__ w_hh,
                            unsigned short* __restrict__ Wg, int* __restrict__ deg4,
                            int total4, int nb_cvt, int n4) {
    int b = blockIdx.x, tt = threadIdx.x;
    if (b < nb_cvt) {
        int i = b * 256 + tt;
        if (i < total4) {
            float4 v = ((const float4*)h)[i];
            uint2 o;
            o.x = (unsigned int)f2bf(v.x) | ((unsigned int)f2bf(v.y) << 16);
            o.y = (unsigned int)f2bf(v.z) | ((unsigned int)f2bf(v.w) << 16);
            ((uint2*)hbf)[i] = o;
        }
    } else if (b < nb_cvt + 256) {
        // Wcat[j][t*128+k] = edge_W[t][j][k]  (128 x 512)
        int idx = (b - nb_cvt) * 256 + tt;
        int j = idx >> 9, rem = idx & 511;
        int t = rem >> 7, k = rem & 127;
        Wc[idx] = f2bf(W[(t * HID + j) * HID + k]);
    } else if (b < nb_cvt + 256 + 512) {
        // Wg[512][256]: rows 4j+{0,1,2,3} = r|z|i_n|h_n
        int idx = (b - nb_cvt - 256) * 256 + tt;
        int row = idx >> 8, k = idx & 255;
        int j = row >> 2, g = row & 3;
        float v = 0.0f;
        if (g == 0) v = (k < 128) ? w_ih[j * 128 + k]         : w_hh[j * 128 + (k - 128)];
        else if (g == 1) v = (k < 128) ? w_ih[(128 + j) * 128 + k] : w_hh[(128 + j) * 128 + (k - 128)];
        else if (g == 2) v = (k < 128) ? w_ih[(256 + j) * 128 + k] : 0.0f;
        else             v = (k < 128) ? 0.0f : w_hh[(256 + j) * 128 + (k - 128)];
        Wg[idx] = f2bf(v);
    } else {
        int i = (b - nb_cvt - 768) * 256 + tt;
        if (i < n4) deg4[i] = 0;
    }
}

// ---- CSR (type-segmented) construction ------------------------------------

__global__ void hist4_kernel(const int* __restrict__ dst, const int* __restrict__ ety,
                             int* __restrict__ deg4, int E) {
    int e = blockIdx.x * blockDim.x + threadIdx.x;
    if (e < E) atomicAdd(&deg4[dst[e] * 4 + ety[e]], 1);
}

// 1024 elements per block (4 per thread) exclusive scan
__global__ void scan_blocks4_kernel(const int* __restrict__ deg, int* __restrict__ rowptr,
                                    int* __restrict__ blocksum, int N4) {
    __shared__ int s[256];
    int t = threadIdx.x;
    int base = blockIdx.x * 1024 + t * 4;
    int v0 = 0, v1 = 0, v2 = 0, v3 = 0;
    if (base + 3 < N4) {
        v0 = deg[base]; v1 = deg[base + 1]; v2 = deg[base + 2]; v3 = deg[base + 3];
    } else {
        if (base < N4) v0 = deg[base];
        if (base + 1 < N4) v1 = deg[base + 1];
        if (base + 2 < N4) v2 = deg[base + 2];
    }
    int sum = v0 + v1 + v2 + v3;
    s[t] = sum;
    __syncthreads();
#pragma unroll
    for (int off = 1; off < 256; off <<= 1) {
        int x = (t >= off) ? s[t - off] : 0;
        __syncthreads();
        s[t] += x;
        __syncthreads();
    }
    int ex = s[t] - sum;
    if (base < N4) rowptr[base] = ex;
    if (base + 1 < N4) rowptr[base + 1] = ex + v0;
    if (base + 2 < N4) rowptr[base + 2] = ex + v0 + v1;
    if (base + 3 < N4) rowptr[base + 3] = ex + v0 + v1 + v2;
    if (t == 255) blocksum[blockIdx.x] = s[255];
}

__global__ void scan_top_kernel(const int* __restrict__ blocksum, int* __restrict__ blockoff, int nb) {
    __shared__ int s[256];
    int t = threadIdx.x;
    int v = (t < nb) ? blocksum[t] : 0;
    s[t] = v;
    __syncthreads();
#pragma unroll
    for (int off = 1; off < 256; off <<= 1) {
        int x = (t >= off) ? s[t - off] : 0;
        __syncthreads();
        s[t] += x;
        __syncthreads();
    }
    if (t < nb) blockoff[t] = s[t] - v;
}

__global__ void finalize4_kernel(int* __restrict__ rowptr, const int* __restrict__ blockoff,
                                 int* __restrict__ cursor, int N4, int E) {
    int i = blockIdx.x * blockDim.x + threadIdx.x;
    if (i >= N4) return;
    int r = rowptr[i] + blockoff[i >> 10];
    rowptr[i] = r;
    cursor[i] = r;
    if (i == 0) rowptr[N4] = E;  // sentinel
}

__global__ void fill4_kernel(const int* __restrict__ src, const int* __restrict__ dst,
                             const int* __restrict__ ety, int* __restrict__ cursor,
                             int* __restrict__ csr, int E) {
    int e = blockIdx.x * blockDim.x + threadIdx.x;
    if (e >= E) return;
    int pos = atomicAdd(&cursor[dst[e] * 4 + ety[e]], 1);
    csr[pos] = src[e];
}

// ---- spmm_gemm: aggbf = (scatter-sum h by type) @ Wcat^T + deg*b ----------
// 64-node tile, 4 waves.  Per K-chunk t: wave w gathers nodes [w*16,w*16+16)
// type-t neighbor hbf rows into Ss (lane owns cols 2l,2l+1, fp32 acc in
// regs, bf16 into LDS), barrier, MFMA A=Ss vs B=Wcat chunk t (wave w owns
// j cols [w*32,w*32+32)), barrier.  Bias via segment lengths in cntS.

__global__ __launch_bounds__(256) void spmm_gemm(const int* __restrict__ rowptr4,
                                                 const int* __restrict__ csr,
                                                 const unsigned int* __restrict__ hbu,
                                                 const unsigned short* __restrict__ Wc,
                                                 const float* __restrict__ eb,
                                                 unsigned short* __restrict__ aggbf, int M) {
    __shared__ __align__(16) unsigned short Ss[64][136];
    __shared__ float cntS[64][4];
    const int tid = threadIdx.x;
    const int m0 = blockIdx.x * 64;
    const int lane = tid & 63, w = tid >> 6;
    const int lm = lane & 15, quad = lane >> 4;
    unsigned int* Ssu = (unsigned int*)&Ss[0][0];  // row stride 68 uints

    floatx4 acc[4][2];
#pragma unroll
    for (int a = 0; a < 4; ++a)
#pragma unroll
        for (int b = 0; b < 2; ++b) acc[a][b] = (floatx4){0.f, 0.f, 0.f, 0.f};

    for (int t = 0; t < NTY; ++t) {
        // gather phase: wave w fills rows [w*16, w*16+16)
#pragma unroll 1
        for (int rl = 0; rl < 16; ++rl) {
            int r = w * 16 + rl;
            int node = m0 + r;
            float a0 = 0.f, a1 = 0.f;
            int len = 0;
            if (node < M) {
                int s0 = rowptr4[node * 4 + t];
                int s1 = rowptr4[node * 4 + t + 1];
                len = s1 - s0;
                int e = s0;
                for (; e + 4 <= s1; e += 4) {
                    int n0e = csr[e], n1e = csr[e + 1], n2e = csr[e + 2], n3e = csr[e + 3];
                    unsigned int u0 = hbu[(size_t)n0e * 64 + lane];
                    unsigned int u1 = hbu[(size_t)n1e * 64 + lane];
                    unsigned int u2 = hbu[(size_t)n2e * 64 + lane];
                    unsigned int u3 = hbu[(size_t)n3e * 64 + lane];
                    a0 += bf2f(u0 & 0xffffu) + bf2f(u1 & 0xffffu) + bf2f(u2 & 0xffffu) + bf2f(u3 & 0xffffu);
                    a1 += bf2f(u0 >> 16) + bf2f(u1 >> 16) + bf2f(u2 >> 16) + bf2f(u3 >> 16);
                }
                for (; e < s1; ++e) {
                    unsigned int u = hbu[(size_t)csr[e] * 64 + lane];
                    a0 += bf2f(u & 0xffffu);
                    a1 += bf2f(u >> 16);
                }
            }
            Ssu[r * 68 + lane] = (unsigned int)f2bf(a0) | ((unsigned int)f2bf(a1) << 16);
            if (lane == 0) cntS[r][t] = (float)len;
        }
        __syncthreads();
        // MFMA phase: A rows 0..63, B cols w*32..w*32+31
#pragma unroll
        for (int s = 0; s < 4; ++s) {
            short8 af[4], bfr[2];
#pragma unroll
            for (int mi = 0; mi < 4; ++mi)
                af[mi] = *(const short8*)&Ss[mi * 16 + lm][s * 32 + quad * 8];
#pragma unroll
            for (int ni = 0; ni < 2; ++ni) {
                int j = w * 32 + ni * 16 + lm;
                bfr[ni] = *(const short8*)(Wc + (size_t)j * 512 + t * 128 + s * 32 + quad * 8);
            }
#pragma unroll
            for (int mi = 0; mi < 4; ++mi)
#pragma unroll
                for (int ni = 0; ni < 2; ++ni)
                    acc[mi][ni] = __builtin_amdgcn_mfma_f32_16x16x32_bf16(af[mi], bfr[ni], acc[mi][ni], 0, 0, 0);
        }
        __syncthreads();
    }
    // epilogue: stage bf16 results into Ss, coalesced write
#pragma unroll
    for (int mi = 0; mi < 4; ++mi) {
#pragma unroll
        for (int rr = 0; rr < 4; ++rr) {
            int r = mi * 16 + quad * 4 + rr;
            float c0 = cntS[r][0], c1 = cntS[r][1], c2 = cntS[r][2], c3 = cntS[r][3];
#pragma unroll
            for (int ni = 0; ni < 2; ++ni) {
                int j = w * 32 + ni * 16 + lm;
                float v = acc[mi][ni][rr];
                v += c0 * eb[j] + c1 * eb[HID + j] + c2 * eb[2 * HID + j] + c3 * eb[3 * HID + j];
                Ss[r][j] = f2bf(v);
            }
        }
    }
    __syncthreads();
    {
        int row = tid >> 2;              // 0..63
        int c0 = (tid & 3) * 32;         // shorts
        int node = m0 + row;
        if (node < M) {
#pragma unroll
            for (int i = 0; i < 4; ++i)
                *(uint4*)(aggbf + (size_t)node * HID + c0 + i * 8) = *(const uint4*)&Ss[row][c0 + i * 8];
        }
    }
}

// ---- gemm_gru fused: C'[512 x M] = Wg[512x256] @ X[Mx256]^T ---------------
// Full gate dim per block, 64-node tiles, X read once.  Wave w owns gate
// rows [w*128,(w+1)*128) = j in [w*32,w*32+32).  acc[mi][ni][0..3] =
// (r,z,i_n,h_n) of (node, j).  h for the blend comes from the hbf Xs tile.

__global__ __launch_bounds__(256) void gemm_gru(const unsigned short* __restrict__ Wg,
                                                const unsigned short* __restrict__ aggbf,
                                                const unsigned short* __restrict__ hbf,
                                                const float* __restrict__ b_ih,
                                                const float* __restrict__ b_hh,
                                                float* __restrict__ out, int M) {
    __shared__ __align__(16) unsigned short Xs[64][136];
    __shared__ __align__(16) float Outs[64][132];
    const int tid = threadIdx.x;
    const int n0 = blockIdx.x * 64;
    const int lane = tid & 63, w = tid >> 6;
    const int lm = lane & 15, quad = lane >> 4;

    floatx4 acc[8][4];
#pragma unroll
    for (int a = 0; a < 8; ++a)
#pragma unroll
        for (int b = 0; b < 4; ++b) acc[a][b] = (floatx4){0.f, 0.f, 0.f, 0.f};

    for (int c = 0; c < 2; ++c) {
        const unsigned short* Xp = c ? hbf : aggbf;  // c=1 last: Xs holds hbf at epilogue
        {
            int rr = tid >> 4;         // 0..15
            int cc = (tid & 15) * 8;   // 0..120
#pragma unroll
            for (int p = 0; p < 4; ++p) {
                int r = rr + p * 16;
                int gn = n0 + r;
                uint4 v = {0u, 0u, 0u, 0u};
                if (gn < M) v = *(const uint4*)(Xp + (size_t)gn * HID + cc);
                *(uint4*)&Xs[r][cc] = v;
            }
        }
        __syncthreads();
#pragma unroll
        for (int s = 0; s < 4; ++s) {
            short8 bfr[4];
#pragma unroll
            for (int ni = 0; ni < 4; ++ni)
                bfr[ni] = *(const short8*)&Xs[ni * 16 + lm][s * 32 + quad * 8];
            short8 af[8];
#pragma unroll
            for (int mi = 0; mi < 8; ++mi) {
                int rowg = w * 128 + mi * 16 + lm;
                af[mi] = *(const short8*)(Wg + (size_t)rowg * 256 + c * 128 + s * 32 + quad * 8);
            }
#pragma unroll
            for (int mi = 0; mi < 8; ++mi)
#pragma unroll
                for (int ni = 0; ni < 4; ++ni)
                    acc[mi][ni] = __builtin_amdgcn_mfma_f32_16x16x32_bf16(af[mi], bfr[ni], acc[mi][ni], 0, 0, 0);
        }
        __syncthreads();  // protect Xs restage (c=0->1); after c=1, Xs stays = hbf
    }

    // epilogue: gate row = w*128 + mi*16 + quad*4 + g  ->  j = w*32 + mi*4 + quad
#pragma unroll
    for (int mi = 0; mi < 8; ++mi) {
        int j = w * 32 + mi * 4 + quad;  // 0..127, unique per (w,mi,quad)
        float brj = b_ih[j] + b_hh[j];
        float bzj = b_ih[128 + j] + b_hh[128 + j];
        float bin = b_ih[256 + j];
        float bhn = b_hh[256 + j];
#pragma unroll
        for (int ni = 0; ni < 4; ++ni) {
            int lrow = ni * 16 + lm;
            float g0 = acc[mi][ni][0], g1 = acc[mi][ni][1];
            float g2 = acc[mi][ni][2], g3 = acc[mi][ni][3];
            float r = 1.0f / (1.0f + __expf(-(g0 + brj)));
            float z = 1.0f / (1.0f + __expf(-(g1 + bzj)));
            float nn = tanhf(g2 + bin + r * (g3 + bhn));
            float hv = bf2f((unsigned int)Xs[lrow][j]);  // hbf tile
            Outs[lrow][j] = (1.0f - z) * nn + z * hv;
        }
    }
    __syncthreads();
    // coalesced write: 64 nodes x 128 floats
    {
        int row = tid >> 2;              // 0..63
        int c0 = (tid & 3) * 32;         // 0..96
        int node = n0 + row;
        if (node < M) {
            float* dst = out + (size_t)node * HID + c0;
#pragma unroll
            for (int i = 0; i < 8; ++i)
                *(float4*)(dst + i * 4) = *(const float4*)&Outs[row][c0 + i * 4];
        }
    }
}

// ---------------------------------------------------------------------------

extern "C" void kernel_launch(void* const* d_in, const int* in_sizes, int n_in,
                              void* d_out, int out_size, void* d_ws, size_t ws_size,
                              hipStream_t stream) {
    const float* node_states = (const float*)d_in[0];
    const int*   edge_index  = (const int*)d_in[1];
    const int*   edge_type   = (const int*)d_in[2];
    const float* edge_W      = (const float*)d_in[3];
    const float* edge_b      = (const float*)d_in[4];
    const float* w_ih        = (const float*)d_in[5];
    const float* w_hh        = (const float*)d_in[6];
    const float* b_ih        = (const float*)d_in[7];
    const float* b_hh        = (const float*)d_in[8];

    const int M = in_sizes[0] / HID;      // 50000 nodes
    const int E = in_sizes[1] / 2;        // 625000 edges
    const int N4 = M * 4;                 // 200000 (dst,type) segments
    const int* src = edge_index;
    const int* dst = edge_index + E;

    // workspace layout (~31 MB)
    char* ws = (char*)d_ws;
    size_t off = 0;
    unsigned short* hbf   = (unsigned short*)(ws + off); off += (size_t)M * HID * 2;    // 12.8MB
    unsigned short* aggbf = (unsigned short*)(ws + off); off += (size_t)M * HID * 2;    // 12.8MB
    unsigned short* Wcat  = (unsigned short*)(ws + off); off += (size_t)128 * 512 * 2;  // 128KB
    unsigned short* Wgru  = (unsigned short*)(ws + off); off += (size_t)512 * 256 * 2;  // 256KB
    int* deg4     = (int*)(ws + off); off += (size_t)N4 * 4;
    int* rowptr4  = (int*)(ws + off); off += (size_t)(N4 + 1) * 4;
    int* cursor4  = (int*)(ws + off); off += (size_t)N4 * 4;
    int* blocksum = (int*)(ws + off); off += 256 * 4;
    int* blockoff = (int*)(ws + off); off += 256 * 4;
    int* csr      = (int*)(ws + off); off += (size_t)E * 4;

    const int total4 = M * HID / 4;              // float4 count for cvt
    const int nb_cvt = (total4 + 255) / 256;     // 6250
    const int nb_zero = (N4 + 255) / 256;        // 782
    const int nb_scan = (N4 + 1023) / 1024;      // 196 <= 256

    prep_kernel<<<nb_cvt + 768 + nb_zero, 256, 0, stream>>>(
        node_states, hbf, edge_W, Wcat, w_ih, w_hh, Wgru, deg4, total4, nb_cvt, N4);

    hist4_kernel<<<(E + 255) / 256, 256, 0, stream>>>(dst, edge_type, deg4, E);
    scan_blocks4_kernel<<<nb_scan, 256, 0, stream>>>(deg4, rowptr4, blocksum, N4);
    scan_top_kernel<<<1, 256, 0, stream>>>(blocksum, blockoff, nb_scan);
    finalize4_kernel<<<(N4 + 255) / 256, 256, 0, stream>>>(rowptr4, blockoff, cursor4, N4, E);
    fill4_kernel<<<(E + 255) / 256, 256, 0, stream>>>(src, dst, edge_type, cursor4, csr, E);

    const int nblk = (M + 63) / 64;  // 782
    spmm_gemm<<<nblk, 256, 0, stream>>>(rowptr4, csr, (const unsigned int*)hbf, Wcat,
                                        edge_b, aggbf, M);
    gemm_gru<<<nblk, 256, 0, stream>>>(Wgru, aggbf, hbf, b_ih, b_hh, (float*)d_out, M);
}

// Round 7
// 369.436 us; speedup vs baseline: 1.1361x; 1.1361x over previous
//
#include <hip/hip_runtime.h>

// ---------------------------------------------------------------------------
// GGNN message passing, MI355X/gfx950.  Round 7: revert R6's gather-GEMM
// fusion (serialized the gather: 189us, MfmaUtil 1.3%).  Keep R5's proven
// parallel gather + plain CSR.  Fuse on the DENSE side instead via algebra:
//   gi = msgsum @ (w_ih . Wcat)^T + sum_t cnt_t (w_ih . b_t)
// Precompute Wcomb = w_ih(3dx d) . Wcat -> one K=640 GEMM [Wcomb|Wgh] @
// [S|hbf]^T with fused GRU epilogue replaces agg_gemm + gemm_gru:
// kills aggbf round-trip (25.6MB), one kernel ramp, and the fp32 h read
// (h blended from the staged hbf LDS tile, validated R6).
//
// Pipeline:  prep (cvt_h + zero deg) | compose (Wfull, BeffR) | CSR build
//   (hist/scan/top/finalize/fill, R5) | gather_s (R5: S[n,t*128+k], cnt4)
//   | gru_mega (K=640 GEMM + GRU epilogue -> out).
// ---------------------------------------------------------------------------

typedef __attribute__((ext_vector_type(8))) short short8;
typedef __attribute__((ext_vector_type(4))) float floatx4;

#define HID 128
#define NTY 4

__device__ __forceinline__ unsigned short f2bf(float f) {
    unsigned int u = __float_as_uint(f);
    unsigned int r = (u + 0x7fffu + ((u >> 16) & 1u)) >> 16;  // RNE
    return (unsigned short)r;
}
__device__ __forceinline__ float bf2f(unsigned int lo16) {
    return __uint_as_float(lo16 << 16);
}

// ---- prep: cvt_h | zero deg ------------------------------------------------

__global__ void prep_kernel(const float* __restrict__ h, unsigned short* __restrict__ hbf,
                            int* __restrict__ deg, int total4, int nb_cvt, int N) {
    int b = blockIdx.x, tt = threadIdx.x;
    if (b < nb_cvt) {
        int i = b * 256 + tt;
        if (i < total4) {
            float4 v = ((const float4*)h)[i];
            uint2 o;
            o.x = (unsigned int)f2bf(v.x) | ((unsigned int)f2bf(v.y) << 16);
            o.y = (unsigned int)f2bf(v.z) | ((unsigned int)f2bf(v.w) << 16);
            ((uint2*)hbf)[i] = o;
        }
    } else {
        int i = (b - nb_cvt) * 256 + tt;
        if (i < N) deg[i] = 0;
    }
}

// ---- compose: Wfull[512][640] + BeffR[4][512] ------------------------------
// Gate row 4j+g (g=0 r, 1 z, 2 i_n, 3 h_n), gate index = g*128+j (g<3).
//   Wfull[row][t*128+k]  = sum_j' w_ih[gate][j'] * edge_W[t][j'][k]   (g<3; 0 for g=3)
//   Wfull[row][512+m]    = w_hh[gate_hh][m]  (g in {0,1}: gate, g=3: 256+j; g=2: 0)
//   BeffR[t][row]        = sum_j' w_ih[gate][j'] * edge_b[t][j']      (g<3; 0 for g=3)

__global__ void compose_kernel(const float* __restrict__ w_ih, const float* __restrict__ w_hh,
                               const float* __restrict__ eW, const float* __restrict__ eb,
                               unsigned short* __restrict__ Wfull, float* __restrict__ BeffR) {
    __shared__ float wrow[128];
    int row = blockIdx.x;        // 0..511
    int tt = threadIdx.x;        // 0..255
    int g = row & 3, j = row >> 2;
    if (g < 3) {
        int gate = g * 128 + j;
        if (tt < 128) wrow[tt] = w_ih[gate * 128 + tt];
        __syncthreads();
        for (int cc = tt; cc < 512; cc += 256) {
            int t = cc >> 7, k = cc & 127;
            const float* ew = eW + ((size_t)t * 128) * 128 + k;  // stride 128 over j'
            float s = 0.f;
            for (int jp = 0; jp < 128; ++jp) s += wrow[jp] * ew[(size_t)jp * 128];
            Wfull[(size_t)row * 640 + cc] = f2bf(s);
        }
        if (tt < 128) {
            float v = (g == 2) ? 0.f : w_hh[gate * 128 + tt];
            Wfull[(size_t)row * 640 + 512 + tt] = f2bf(v);
        }
        if (tt >= 128 && tt < 132) {
            int t = tt - 128;
            float s = 0.f;
            for (int jp = 0; jp < 128; ++jp) s += wrow[jp] * eb[t * 128 + jp];
            BeffR[t * 512 + row] = s;
        }
    } else {
        for (int cc = tt; cc < 512; cc += 256) Wfull[(size_t)row * 640 + cc] = 0;
        if (tt < 128) Wfull[(size_t)row * 640 + 512 + tt] = f2bf(w_hh[(256 + j) * 128 + tt]);
        if (tt >= 128 && tt < 132) BeffR[(tt - 128) * 512 + row] = 0.f;
    }
}

// ---- CSR construction (R5) -------------------------------------------------

__global__ void hist_kernel(const int* __restrict__ dst, int* __restrict__ deg, int E) {
    int e = blockIdx.x * blockDim.x + threadIdx.x;
    if (e < E) atomicAdd(&deg[dst[e]], 1);
}

__global__ void scan_blocks_kernel(const int* __restrict__ deg, int* __restrict__ rowptr,
                                   int* __restrict__ blocksum, int N) {
    __shared__ int s[256];
    int t = threadIdx.x;
    int i = blockIdx.x * 256 + t;
    int v = (i < N) ? deg[i] : 0;
    s[t] = v;
    __syncthreads();
#pragma unroll
    for (int off = 1; off < 256; off <<= 1) {
        int x = (t >= off) ? s[t - off] : 0;
        __syncthreads();
        s[t] += x;
        __syncthreads();
    }
    if (i < N) rowptr[i] = s[t] - v;  // exclusive
    if (t == 255) blocksum[blockIdx.x] = s[t];
}

__global__ void scan_top_kernel(const int* __restrict__ blocksum, int* __restrict__ blockoff, int nb) {
    __shared__ int s[256];
    int t = threadIdx.x;
    int v = (t < nb) ? blocksum[t] : 0;
    s[t] = v;
    __syncthreads();
#pragma unroll
    for (int off = 1; off < 256; off <<= 1) {
        int x = (t >= off) ? s[t - off] : 0;
        __syncthreads();
        s[t] += x;
        __syncthreads();
    }
    if (t < nb) blockoff[t] = s[t] - v;
}

__global__ void finalize_kernel(int* __restrict__ rowptr, const int* __restrict__ blockoff,
                                int* __restrict__ cursor, int N) {
    int i = blockIdx.x * blockDim.x + threadIdx.x;
    if (i >= N) return;
    int r = rowptr[i] + blockoff[i >> 8];
    rowptr[i] = r;
    cursor[i] = r;
}

__global__ void fill_kernel(const int* __restrict__ src, const int* __restrict__ dst,
                            const int* __restrict__ ety, int* __restrict__ cursor,
                            int* __restrict__ csr, int E) {
    int e = blockIdx.x * blockDim.x + threadIdx.x;
    if (e >= E) return;
    int pos = atomicAdd(&cursor[dst[e]], 1);
    csr[pos] = (src[e] << 2) | ety[e];
}

// ---- gather_s (R5): S[n, t*128+:] = sum of type-t neighbor hbf rows -------

__device__ __forceinline__ void acc_typed(int pk, unsigned int u,
                                          float& a00, float& a01, float& a10, float& a11,
                                          float& a20, float& a21, float& a30, float& a31) {
    int t = pk & 3;
    float v0 = bf2f(u & 0xffffu), v1 = bf2f(u >> 16);
    a00 += (t == 0) ? v0 : 0.f; a01 += (t == 0) ? v1 : 0.f;
    a10 += (t == 1) ? v0 : 0.f; a11 += (t == 1) ? v1 : 0.f;
    a20 += (t == 2) ? v0 : 0.f; a21 += (t == 2) ? v1 : 0.f;
    a30 += (t == 3) ? v0 : 0.f; a31 += (t == 3) ? v1 : 0.f;
}

__global__ void gather_s_kernel(const int* __restrict__ rowptr, const int* __restrict__ deg,
                                const int* __restrict__ csr, const unsigned int* __restrict__ hbu,
                                float4* __restrict__ cnt4, unsigned int* __restrict__ Su, int N) {
    int w = blockIdx.x * (blockDim.x >> 6) + (threadIdx.x >> 6);
    if (w >= N) return;
    int lane = threadIdx.x & 63;
    int start = rowptr[w];
    int end = start + deg[w];
    float a00 = 0.f, a01 = 0.f, a10 = 0.f, a11 = 0.f;
    float a20 = 0.f, a21 = 0.f, a30 = 0.f, a31 = 0.f;
    unsigned int cpack = 0;
    int e = start;
    for (; e + 8 <= end; e += 8) {
        int p[8];
        unsigned int u[8];
#pragma unroll
        for (int i = 0; i < 8; ++i) p[i] = csr[e + i];
#pragma unroll
        for (int i = 0; i < 8; ++i) u[i] = hbu[(size_t)(p[i] >> 2) * 64 + lane];
#pragma unroll
        for (int i = 0; i < 8; ++i) {
            cpack += 1u << ((p[i] & 3) << 3);
            acc_typed(p[i], u[i], a00, a01, a10, a11, a20, a21, a30, a31);
        }
    }
    for (; e + 4 <= end; e += 4) {
        int p[4];
        unsigned int u[4];
#pragma unroll
        for (int i = 0; i < 4; ++i) p[i] = csr[e + i];
#pragma unroll
        for (int i = 0; i < 4; ++i) u[i] = hbu[(size_t)(p[i] >> 2) * 64 + lane];
#pragma unroll
        for (int i = 0; i < 4; ++i) {
            cpack += 1u << ((p[i] & 3) << 3);
            acc_typed(p[i], u[i], a00, a01, a10, a11, a20, a21, a30, a31);
        }
    }
    for (; e < end; ++e) {
        int pk = csr[e];
        unsigned int u = hbu[(size_t)(pk >> 2) * 64 + lane];
        cpack += 1u << ((pk & 3) << 3);
        acc_typed(pk, u, a00, a01, a10, a11, a20, a21, a30, a31);
    }
    size_t base = (size_t)w * 256 + lane;
    Su[base]       = (unsigned int)f2bf(a00) | ((unsigned int)f2bf(a01) << 16);
    Su[base + 64]  = (unsigned int)f2bf(a10) | ((unsigned int)f2bf(a11) << 16);
    Su[base + 128] = (unsigned int)f2bf(a20) | ((unsigned int)f2bf(a21) << 16);
    Su[base + 192] = (unsigned int)f2bf(a30) | ((unsigned int)f2bf(a31) << 16);
    if (lane == 0)
        cnt4[w] = make_float4((float)(cpack & 255u), (float)((cpack >> 8) & 255u),
                              (float)((cpack >> 16) & 255u), (float)(cpack >> 24));
}

// ---- gru_mega: C'[512 x M] = Wfull[512x640] @ [S|hbf][Mx640]^T + GRU ------
// 64-node tiles, 4 waves; wave w owns gate rows [w*128,(w+1)*128) = j in
// [w*32,w*32+32).  acc[mi][ni][0..3] = (r,z,i_n,h_n) pre-acts of (node,j).
// K chunks: c=0..3 from S, c=4 from hbf (so Xs holds hbf at epilogue for the
// blend).  cnt-bias via BeffR; out via fp32 LDS tile, coalesced stores.

__global__ __launch_bounds__(256) void gru_mega(const unsigned short* __restrict__ Wfull,
                                                const unsigned short* __restrict__ S,
                                                const unsigned short* __restrict__ hbf,
                                                const float4* __restrict__ cnt4,
                                                const float* __restrict__ BeffR,
                                                const float* __restrict__ b_ih,
                                                const float* __restrict__ b_hh,
                                                float* __restrict__ out, int M) {
    __shared__ __align__(16) unsigned short Xs[64][136];
    __shared__ __align__(16) float Outs[64][132];
    const int tid = threadIdx.x;
    const int n0 = blockIdx.x * 64;
    const int lane = tid & 63, w = tid >> 6;
    const int lm = lane & 15, quad = lane >> 4;

    floatx4 acc[8][4];
#pragma unroll
    for (int a = 0; a < 8; ++a)
#pragma unroll
        for (int b = 0; b < 4; ++b) acc[a][b] = (floatx4){0.f, 0.f, 0.f, 0.f};

    for (int c = 0; c < 5; ++c) {
        {
            int rr = tid >> 4;         // 0..15
            int cc = (tid & 15) * 8;   // 0..120
#pragma unroll
            for (int p = 0; p < 4; ++p) {
                int r = rr + p * 16;
                int gn = n0 + r;
                uint4 v = {0u, 0u, 0u, 0u};
                if (gn < M)
                    v = (c < 4) ? *(const uint4*)(S + (size_t)gn * 512 + c * 128 + cc)
                                : *(const uint4*)(hbf + (size_t)gn * HID + cc);
                *(uint4*)&Xs[r][cc] = v;
            }
        }
        __syncthreads();
#pragma unroll
        for (int s = 0; s < 4; ++s) {
            short8 bfr[4];
#pragma unroll
            for (int ni = 0; ni < 4; ++ni)
                bfr[ni] = *(const short8*)&Xs[ni * 16 + lm][s * 32 + quad * 8];
            short8 af[8];
#pragma unroll
            for (int mi = 0; mi < 8; ++mi) {
                int rowg = w * 128 + mi * 16 + lm;
                af[mi] = *(const short8*)(Wfull + (size_t)rowg * 640 + c * 128 + s * 32 + quad * 8);
            }
#pragma unroll
            for (int mi = 0; mi < 8; ++mi)
#pragma unroll
                for (int ni = 0; ni < 4; ++ni)
                    acc[mi][ni] = __builtin_amdgcn_mfma_f32_16x16x32_bf16(af[mi], bfr[ni], acc[mi][ni], 0, 0, 0);
        }
        __syncthreads();  // after c=4 Xs stays = hbf for the blend
    }

    // epilogue: gate row = w*128 + mi*16 + quad*4 + g  ->  j = w*32 + mi*4 + quad
#pragma unroll
    for (int mi = 0; mi < 8; ++mi) {
        int j = w * 32 + mi * 4 + quad;  // 0..127
        int r0 = 4 * j;                  // gate-row base
        float brj = b_ih[j] + b_hh[j];
        float bzj = b_ih[128 + j] + b_hh[128 + j];
        float bin = b_ih[256 + j];
        float bhn = b_hh[256 + j];
        float B0r = BeffR[r0],           B0z = BeffR[r0 + 1],           B0n = BeffR[r0 + 2];
        float B1r = BeffR[512 + r0],     B1z = BeffR[512 + r0 + 1],     B1n = BeffR[512 + r0 + 2];
        float B2r = BeffR[1024 + r0],    B2z = BeffR[1024 + r0 + 1],    B2n = BeffR[1024 + r0 + 2];
        float B3r = BeffR[1536 + r0],    B3z = BeffR[1536 + r0 + 1],    B3n = BeffR[1536 + r0 + 2];
#pragma unroll
        for (int ni = 0; ni < 4; ++ni) {
            int lrow = ni * 16 + lm;
            int node = n0 + lrow;
            float4 c4 = (node < M) ? cnt4[node] : make_float4(0.f, 0.f, 0.f, 0.f);
            float pre_r = acc[mi][ni][0] + brj + c4.x * B0r + c4.y * B1r + c4.z * B2r + c4.w * B3r;
            float pre_z = acc[mi][ni][1] + bzj + c4.x * B0z + c4.y * B1z + c4.z * B2z + c4.w * B3z;
            float pre_n = acc[mi][ni][2] + bin + c4.x * B0n + c4.y * B1n + c4.z * B2n + c4.w * B3n;
            float pre_h = acc[mi][ni][3] + bhn;
            float r = 1.0f / (1.0f + __expf(-pre_r));
            float z = 1.0f / (1.0f + __expf(-pre_z));
            float nn = tanhf(pre_n + r * pre_h);
            float hv = bf2f((unsigned int)Xs[lrow][j]);
            Outs[lrow][j] = (1.0f - z) * nn + z * hv;
        }
    }
    __syncthreads();
    {
        int row = tid >> 2;              // 0..63
        int c0 = (tid & 3) * 32;         // 0..96
        int node = n0 + row;
        if (node < M) {
            float* dst = out + (size_t)node * HID + c0;
#pragma unroll
            for (int i = 0; i < 8; ++i)
                *(float4*)(dst + i * 4) = *(const float4*)&Outs[row][c0 + i * 4];
        }
    }
}

// ---------------------------------------------------------------------------

extern "C" void kernel_launch(void* const* d_in, const int* in_sizes, int n_in,
                              void* d_out, int out_size, void* d_ws, size_t ws_size,
                              hipStream_t stream) {
    const float* node_states = (const float*)d_in[0];
    const int*   edge_index  = (const int*)d_in[1];
    const int*   edge_type   = (const int*)d_in[2];
    const float* edge_W      = (const float*)d_in[3];
    const float* edge_b      = (const float*)d_in[4];
    const float* w_ih        = (const float*)d_in[5];
    const float* w_hh        = (const float*)d_in[6];
    const float* b_ih        = (const float*)d_in[7];
    const float* b_hh        = (const float*)d_in[8];

    const int M = in_sizes[0] / HID;      // 50000 nodes
    const int E = in_sizes[1] / 2;        // 625000 edges
    const int* src = edge_index;
    const int* dst = edge_index + E;

    // workspace layout (~69 MB)
    char* ws = (char*)d_ws;
    size_t off = 0;
    unsigned short* hbf   = (unsigned short*)(ws + off); off += (size_t)M * HID * 2;    // 12.8MB
    unsigned short* S     = (unsigned short*)(ws + off); off += (size_t)M * 512 * 2;    // 51.2MB
    unsigned short* Wfull = (unsigned short*)(ws + off); off += (size_t)512 * 640 * 2;  // 640KB
    float*          BeffR = (float*)(ws + off);          off += (size_t)4 * 512 * 4;    // 8KB
    float*          cnt4  = (float*)(ws + off);          off += (size_t)M * 4 * 4;      // 800KB
    int* deg      = (int*)(ws + off); off += (size_t)M * 4;
    int* rowptr   = (int*)(ws + off); off += (size_t)M * 4;
    int* cursor   = (int*)(ws + off); off += (size_t)M * 4;
    int* blocksum = (int*)(ws + off); off += 256 * 4;
    int* blockoff = (int*)(ws + off); off += 256 * 4;
    int* csr      = (int*)(ws + off); off += (size_t)E * 4;

    const int total4 = M * HID / 4;
    const int nb_cvt = (total4 + 255) / 256;
    const int nb_zero = (M + 255) / 256;
    const int nb = (M + 255) / 256;  // 196 <= 256

    prep_kernel<<<nb_cvt + nb_zero, 256, 0, stream>>>(node_states, hbf, deg, total4, nb_cvt, M);
    compose_kernel<<<512, 256, 0, stream>>>(w_ih, w_hh, edge_W, edge_b, Wfull, BeffR);

    hist_kernel<<<(E + 255) / 256, 256, 0, stream>>>(dst, deg, E);
    scan_blocks_kernel<<<nb, 256, 0, stream>>>(deg, rowptr, blocksum, M);
    scan_top_kernel<<<1, 256, 0, stream>>>(blocksum, blockoff, nb);
    finalize_kernel<<<(M + 255) / 256, 256, 0, stream>>>(rowptr, blockoff, cursor, M);
    fill_kernel<<<(E + 255) / 256, 256, 0, stream>>>(src, dst, edge_type, cursor, csr, E);

    gather_s_kernel<<<(M + 3) / 4, 256, 0, stream>>>(rowptr, deg, csr, (const unsigned int*)hbf,
                                                     (float4*)cnt4, (unsigned int*)S, M);

    gru_mega<<<(M + 63) / 64, 256, 0, stream>>>(Wfull, S, hbf, (const float4*)cnt4, BeffR,
                                                b_ih, b_hh, (float*)d_out, M);
}

// Round 8
// 311.653 us; speedup vs baseline: 1.3467x; 1.1854x over previous
//
#include <hip/hip_runtime.h>

// ---------------------------------------------------------------------------
// GGNN message passing, MI355X/gfx950.  Round 8 = R5 (best, 299.6us) plus:
//   - pair-edge gather: half-waves own alternating edges, uint2 (8B) loads,
//     16 edges in flight, shfl_xor(32) merge  (R5 loaded 4B/edge/lane).
//   - gemm_gru blends h from the staged hbf LDS tile (kills 25.6MB fp32 read;
//     validated R6/R7, absmax 0.031 vs 0.023 — threshold 0.106).
//   - agg_gemm: Wcat fragments hoisted to K-chunk top (issue before barrier).
//   - prep merged into one dispatch (cvt_h | pack_wcat | pack_wgru | zero deg).
// R6/R7 lessons kept: no gather-into-GEMM fusion (serializes the gather);
// no K-dim merging (GEMM time scales with K in this latency-bound family).
//
// Dataflow:
//   S[n, t*128+k] = sum_{e: dst=n, t_e=t} hbf[src_e][k]   (CSR gather)
//   aggbf = S @ Wcat^T + cnt*b                            (K=512 GEMM)
//   out   = GRU via C' = Wg[512x256] @ [aggbf|hbf]^T, gate rows 4j+{r,z,n,h}
//           -> one lane's 4 acc regs, fused nonlinearity, LDS-staged stores.
// ---------------------------------------------------------------------------

typedef __attribute__((ext_vector_type(8))) short short8;
typedef __attribute__((ext_vector_type(4))) float floatx4;

#define HID 128
#define NTY 4

__device__ __forceinline__ unsigned short f2bf(float f) {
    unsigned int u = __float_as_uint(f);
    unsigned int r = (u + 0x7fffu + ((u >> 16) & 1u)) >> 16;  // RNE
    return (unsigned short)r;
}
__device__ __forceinline__ float bf2f(unsigned int lo16) {
    return __uint_as_float(lo16 << 16);
}

// ---- prep: cvt_h | pack_wcat | pack_wgru | zero deg, one dispatch ---------

__global__ void prep_kernel(const float* __restrict__ h, unsigned short* __restrict__ hbf,
                            const float* __restrict__ W, unsigned short* __restrict__ Wc,
                            const float* __restrict__ w_ih, const float* __restrict__ w_hh,
                            unsigned short* __restrict__ Wg, int* __restrict__ deg,
                            int total4, int nb_cvt, int N) {
    int b = blockIdx.x, tt = threadIdx.x;
    if (b < nb_cvt) {
        int i = b * 256 + tt;
        if (i < total4) {
            float4 v = ((const float4*)h)[i];
            uint2 o;
            o.x = (unsigned int)f2bf(v.x) | ((unsigned int)f2bf(v.y) << 16);
            o.y = (unsigned int)f2bf(v.z) | ((unsigned int)f2bf(v.w) << 16);
            ((uint2*)hbf)[i] = o;
        }
    } else if (b < nb_cvt + 256) {
        // Wcat[j][t*128+k] = edge_W[t][j][k]  (128 x 512)
        int idx = (b - nb_cvt) * 256 + tt;
        int j = idx >> 9, rem = idx & 511;
        int t = rem >> 7, k = rem & 127;
        Wc[idx] = f2bf(W[(t * HID + j) * HID + k]);
    } else if (b < nb_cvt + 768) {
        // Wg[512][256]: rows 4j+{0,1,2,3} = r|z|i_n|h_n
        int idx = (b - nb_cvt - 256) * 256 + tt;
        int row = idx >> 8, k = idx & 255;
        int j = row >> 2, g = row & 3;
        float v = 0.0f;
        if (g == 0) v = (k < 128) ? w_ih[j * 128 + k]         : w_hh[j * 128 + (k - 128)];
        else if (g == 1) v = (k < 128) ? w_ih[(128 + j) * 128 + k] : w_hh[(128 + j) * 128 + (k - 128)];
        else if (g == 2) v = (k < 128) ? w_ih[(256 + j) * 128 + k] : 0.0f;
        else             v = (k < 128) ? 0.0f : w_hh[(256 + j) * 128 + (k - 128)];
        Wg[idx] = f2bf(v);
    } else {
        int i = (b - nb_cvt - 768) * 256 + tt;
        if (i < N) deg[i] = 0;
    }
}

// ---- CSR construction (R5) -------------------------------------------------

__global__ void hist_kernel(const int* __restrict__ dst, int* __restrict__ deg, int E) {
    int e = blockIdx.x * blockDim.x + threadIdx.x;
    if (e < E) atomicAdd(&deg[dst[e]], 1);
}

__global__ void scan_blocks_kernel(const int* __restrict__ deg, int* __restrict__ rowptr,
                                   int* __restrict__ blocksum, int N) {
    __shared__ int s[256];
    int t = threadIdx.x;
    int i = blockIdx.x * 256 + t;
    int v = (i < N) ? deg[i] : 0;
    s[t] = v;
    __syncthreads();
#pragma unroll
    for (int off = 1; off < 256; off <<= 1) {
        int x = (t >= off) ? s[t - off] : 0;
        __syncthreads();
        s[t] += x;
        __syncthreads();
    }
    if (i < N) rowptr[i] = s[t] - v;  // exclusive
    if (t == 255) blocksum[blockIdx.x] = s[t];
}

__global__ void scan_top_kernel(const int* __restrict__ blocksum, int* __restrict__ blockoff, int nb) {
    __shared__ int s[256];
    int t = threadIdx.x;
    int v = (t < nb) ? blocksum[t] : 0;
    s[t] = v;
    __syncthreads();
#pragma unroll
    for (int off = 1; off < 256; off <<= 1) {
        int x = (t >= off) ? s[t - off] : 0;
        __syncthreads();
        s[t] += x;
        __syncthreads();
    }
    if (t < nb) blockoff[t] = s[t] - v;
}

__global__ void finalize_kernel(int* __restrict__ rowptr, const int* __restrict__ blockoff,
                                int* __restrict__ cursor, int N) {
    int i = blockIdx.x * blockDim.x + threadIdx.x;
    if (i >= N) return;
    int r = rowptr[i] + blockoff[i >> 8];
    rowptr[i] = r;
    cursor[i] = r;
}

__global__ void fill_kernel(const int* __restrict__ src, const int* __restrict__ dst,
                            const int* __restrict__ ety, int* __restrict__ cursor,
                            int* __restrict__ csr, int E) {
    int e = blockIdx.x * blockDim.x + threadIdx.x;
    if (e >= E) return;
    int pos = atomicAdd(&cursor[dst[e]], 1);
    csr[pos] = (src[e] << 2) | ety[e];
}

// ---- gather_s v2: pair-edge.  Half-wave h owns edge e+h; lane covers cols
// [4l, 4l+4) of its half's row via one uint2 (8B) load.  16 edges in flight.
// shfl_xor(32) merges the halves; lanes 0-31 write S + cnt4.

__global__ void gather_s_kernel(const int* __restrict__ rowptr, const int* __restrict__ deg,
                                const int* __restrict__ csr, const uint2* __restrict__ hb2,
                                float4* __restrict__ cnt4, uint2* __restrict__ Su2, int N) {
    int w = blockIdx.x * (blockDim.x >> 6) + (threadIdx.x >> 6);
    if (w >= N) return;
    int lane = threadIdx.x & 63;
    int half = lane >> 5, l = lane & 31;
    int start = rowptr[w];
    int end = start + deg[w];
    float a[4][4];
#pragma unroll
    for (int t = 0; t < 4; ++t)
#pragma unroll
        for (int v = 0; v < 4; ++v) a[t][v] = 0.f;
    unsigned int cpack = 0;
    int e = start;
    for (; e + 16 <= end; e += 16) {  // 8 pairs
        int pk[8];
        uint2 u[8];
#pragma unroll
        for (int i = 0; i < 8; ++i) pk[i] = csr[e + 2 * i + half];
#pragma unroll
        for (int i = 0; i < 8; ++i) u[i] = hb2[(size_t)(pk[i] >> 2) * 32 + l];
#pragma unroll
        for (int i = 0; i < 8; ++i) {
            cpack += 1u << ((pk[i] & 3) << 3);
            int t = pk[i] & 3;
            float v0 = bf2f(u[i].x & 0xffffu), v1 = bf2f(u[i].x >> 16);
            float v2 = bf2f(u[i].y & 0xffffu), v3 = bf2f(u[i].y >> 16);
#pragma unroll
            for (int tt = 0; tt < 4; ++tt) {
                bool m = (t == tt);
                a[tt][0] += m ? v0 : 0.f; a[tt][1] += m ? v1 : 0.f;
                a[tt][2] += m ? v2 : 0.f; a[tt][3] += m ? v3 : 0.f;
            }
        }
    }
    for (; e < end; e += 2) {  // masked pair tail
        int idx = e + half;
        bool valid = idx < end;
        int pk = csr[valid ? idx : e];
        uint2 u = hb2[(size_t)(pk >> 2) * 32 + l];
        if (valid) {
            cpack += 1u << ((pk & 3) << 3);
            int t = pk & 3;
            float v0 = bf2f(u.x & 0xffffu), v1 = bf2f(u.x >> 16);
            float v2 = bf2f(u.y & 0xffffu), v3 = bf2f(u.y >> 16);
#pragma unroll
            for (int tt = 0; tt < 4; ++tt) {
                bool m = (t == tt);
                a[tt][0] += m ? v0 : 0.f; a[tt][1] += m ? v1 : 0.f;
                a[tt][2] += m ? v2 : 0.f; a[tt][3] += m ? v3 : 0.f;
            }
        }
    }
    // merge halves
#pragma unroll
    for (int tt = 0; tt < 4; ++tt)
#pragma unroll
        for (int v = 0; v < 4; ++v) a[tt][v] += __shfl_xor(a[tt][v], 32);
    cpack += __shfl_xor(cpack, 32);
    if (half == 0) {
        uint2* dstp = Su2 + (size_t)w * 128;  // S row: 256 uints = 128 uint2
#pragma unroll
        for (int tt = 0; tt < 4; ++tt) {
            uint2 o;
            o.x = (unsigned int)f2bf(a[tt][0]) | ((unsigned int)f2bf(a[tt][1]) << 16);
            o.y = (unsigned int)f2bf(a[tt][2]) | ((unsigned int)f2bf(a[tt][3]) << 16);
            dstp[tt * 32 + l] = o;
        }
        if (l == 0)
            cnt4[w] = make_float4((float)(cpack & 255u), (float)((cpack >> 8) & 255u),
                                  (float)((cpack >> 16) & 255u), (float)(cpack >> 24));
    }
}

// ---- agg_gemm: aggbf[M x 128] = S[M x 512] @ Wcat[128 x 512]^T + bias -----
// 128-node tile, Wcat frags hoisted to chunk top, LDS-staged coalesced store.

__global__ __launch_bounds__(256) void agg_gemm(const unsigned short* __restrict__ S,
                                                const unsigned short* __restrict__ Wc,
                                                const float4* __restrict__ cnt4,
                                                const float* __restrict__ eb,
                                                unsigned short* __restrict__ aggbf, int M) {
    __shared__ __align__(16) unsigned short Ss[128][136];
    const int tid = threadIdx.x;
    const int m0 = blockIdx.x * 128;
    const int lane = tid & 63, wave = tid >> 6;
    const int wm = wave >> 1, wn = wave & 1;
    const int lm = lane & 15, quad = lane >> 4;

    floatx4 acc[4][4];
#pragma unroll
    for (int a = 0; a < 4; ++a)
#pragma unroll
        for (int b = 0; b < 4; ++b) acc[a][b] = (floatx4){0.f, 0.f, 0.f, 0.f};

    for (int c = 0; c < 4; ++c) {  // K = 512, BK = 128
        // hoisted weight fragments for this chunk (issue before the barrier)
        short8 bfr[4][4];
#pragma unroll
        for (int s = 0; s < 4; ++s)
#pragma unroll
            for (int ni = 0; ni < 4; ++ni) {
                int j = wn * 64 + ni * 16 + lm;
                bfr[s][ni] = *(const short8*)(Wc + (size_t)j * 512 + c * 128 + s * 32 + quad * 8);
            }
        {
            int rr = tid >> 4;
            int cc = (tid & 15) * 8;
#pragma unroll
            for (int p = 0; p < 8; ++p) {
                int r = rr + p * 16;
                int gm = m0 + r;
                uint4 v = {0u, 0u, 0u, 0u};
                if (gm < M) v = *(const uint4*)(S + (size_t)gm * 512 + c * 128 + cc);
                *(uint4*)&Ss[r][cc] = v;
            }
        }
        __syncthreads();
#pragma unroll
        for (int s = 0; s < 4; ++s) {
            short8 af[4];
#pragma unroll
            for (int mi = 0; mi < 4; ++mi)
                af[mi] = *(const short8*)&Ss[wm * 64 + mi * 16 + lm][s * 32 + quad * 8];
#pragma unroll
            for (int mi = 0; mi < 4; ++mi)
#pragma unroll
                for (int ni = 0; ni < 4; ++ni)
                    acc[mi][ni] = __builtin_amdgcn_mfma_f32_16x16x32_bf16(af[mi], bfr[s][ni], acc[mi][ni], 0, 0, 0);
        }
        __syncthreads();
    }
    // epilogue: stage bf16 results into Ss, coalesced write
#pragma unroll
    for (int mi = 0; mi < 4; ++mi) {
        int row_b = wm * 64 + mi * 16 + quad * 4;
#pragma unroll
        for (int r = 0; r < 4; ++r) {
            int lrow = row_b + r;
            int node = m0 + lrow;
            float4 c4 = (node < M) ? cnt4[node] : make_float4(0.f, 0.f, 0.f, 0.f);
#pragma unroll
            for (int ni = 0; ni < 4; ++ni) {
                int j = wn * 64 + ni * 16 + lm;
                float v = acc[mi][ni][r];
                v += c4.x * eb[j] + c4.y * eb[HID + j] + c4.z * eb[2 * HID + j] + c4.w * eb[3 * HID + j];
                Ss[lrow][j] = f2bf(v);
            }
        }
    }
    __syncthreads();
    {
        int row = tid >> 1;              // 0..127
        int halfc = (tid & 1) * 64;      // shorts
        int node = m0 + row;
        if (node < M) {
#pragma unroll
            for (int i = 0; i < 8; ++i)
                *(uint4*)(aggbf + (size_t)node * HID + halfc + i * 8) = *(const uint4*)&Ss[row][halfc + i * 8];
        }
    }
}

// ---- gemm_gru (R5 + h-from-LDS): C'[512 x M] = Wg @ [aggbf|hbf]^T ---------
// grid.y = gate-half; 64-node tiles; wave w owns 64 gate rows x 64 nodes.
// acc[mi][ni][0..3] = (r,z,i_n,h_n) of (node, j).  h blended from the hbf
// Xs tile (staged last).  Out via fp32 LDS tile, coalesced float4 stores.

__global__ __launch_bounds__(256) void gemm_gru(const unsigned short* __restrict__ Wg,
                                                const unsigned short* __restrict__ aggbf,
                                                const unsigned short* __restrict__ hbf,
                                                const float* __restrict__ b_ih,
                                                const float* __restrict__ b_hh,
                                                float* __restrict__ out, int M) {
    __shared__ __align__(16) unsigned short Xs[64][136];
    __shared__ __align__(16) float Outs[64][68];
    const int tid = threadIdx.x;
    const int n0 = blockIdx.x * 64;       // node tile
    const int gh = blockIdx.y;            // gate half: rows [gh*256, gh*256+256)
    const int lane = tid & 63, w = tid >> 6;
    const int lm = lane & 15, quad = lane >> 4;

    floatx4 acc[4][4];
#pragma unroll
    for (int a = 0; a < 4; ++a)
#pragma unroll
        for (int b = 0; b < 4; ++b) acc[a][b] = (floatx4){0.f, 0.f, 0.f, 0.f};

    for (int c = 0; c < 2; ++c) {
        const unsigned short* Xp = c ? hbf : aggbf;  // hbf last -> Xs = hbf at epilogue
        {
            int rr = tid >> 4;         // 0..15
            int cc = (tid & 15) * 8;   // 0..120
#pragma unroll
            for (int p = 0; p < 4; ++p) {
                int r = rr + p * 16;   // 0..63
                int gn = n0 + r;
                uint4 v = {0u, 0u, 0u, 0u};
                if (gn < M) v = *(const uint4*)(Xp + (size_t)gn * HID + cc);
                *(uint4*)&Xs[r][cc] = v;
            }
        }
        __syncthreads();
#pragma unroll
        for (int s = 0; s < 4; ++s) {
            short8 bfr[4];
#pragma unroll
            for (int ni = 0; ni < 4; ++ni)
                bfr[ni] = *(const short8*)&Xs[ni * 16 + lm][s * 32 + quad * 8];
            short8 af[4];
#pragma unroll
            for (int mi = 0; mi < 4; ++mi) {
                int rowg = gh * 256 + w * 64 + mi * 16 + lm;
                af[mi] = *(const short8*)(Wg + (size_t)rowg * 256 + c * 128 + s * 32 + quad * 8);
            }
#pragma unroll
            for (int mi = 0; mi < 4; ++mi)
#pragma unroll
                for (int ni = 0; ni < 4; ++ni)
                    acc[mi][ni] = __builtin_amdgcn_mfma_f32_16x16x32_bf16(af[mi], bfr[ni], acc[mi][ni], 0, 0, 0);
        }
        __syncthreads();  // protect restage; after c=1, Xs stays = hbf
    }

    // epilogue: gate row = gh*256 + w*64 + mi*16 + quad*4 + g -> j = row>>2
#pragma unroll
    for (int mi = 0; mi < 4; ++mi) {
        int jl = w * 16 + mi * 4 + quad;  // 0..63 within half
        int j = gh * 64 + jl;             // 0..127
        float brj = b_ih[j] + b_hh[j];
        float bzj = b_ih[128 + j] + b_hh[128 + j];
        float bin = b_ih[256 + j];
        float bhn = b_hh[256 + j];
#pragma unroll
        for (int ni = 0; ni < 4; ++ni) {
            int lrow = ni * 16 + lm;
            float g0 = acc[mi][ni][0], g1 = acc[mi][ni][1];
            float g2 = acc[mi][ni][2], g3 = acc[mi][ni][3];
            float r = 1.0f / (1.0f + __expf(-(g0 + brj)));
            float z = 1.0f / (1.0f + __expf(-(g1 + bzj)));
            float nn = tanhf(g2 + bin + r * (g3 + bhn));
            float hv = bf2f((unsigned int)Xs[lrow][j]);  // hbf tile
            Outs[lrow][jl] = (1.0f - z) * nn + z * hv;
        }
    }
    __syncthreads();
    // coalesced write: 64 nodes x 64 floats (256B contiguous per node)
    {
        int row = tid >> 2;              // 0..63
        int c0 = (tid & 3) * 16;         // 0..48
        int node = n0 + row;
        if (node < M) {
            float* dstp = out + (size_t)node * HID + gh * 64 + c0;
#pragma unroll
            for (int i = 0; i < 4; ++i)
                *(float4*)(dstp + i * 4) = *(const float4*)&Outs[row][c0 + i * 4];
        }
    }
}

// ---------------------------------------------------------------------------

extern "C" void kernel_launch(void* const* d_in, const int* in_sizes, int n_in,
                              void* d_out, int out_size, void* d_ws, size_t ws_size,
                              hipStream_t stream) {
    const float* node_states = (const float*)d_in[0];
    const int*   edge_index  = (const int*)d_in[1];
    const int*   edge_type   = (const int*)d_in[2];
    const float* edge_W      = (const float*)d_in[3];
    const float* edge_b      = (const float*)d_in[4];
    const float* w_ih        = (const float*)d_in[5];
    const float* w_hh        = (const float*)d_in[6];
    const float* b_ih        = (const float*)d_in[7];
    const float* b_hh        = (const float*)d_in[8];

    const int M = in_sizes[0] / HID;      // 50000 nodes
    const int E = in_sizes[1] / 2;        // 625000 edges
    const int* src = edge_index;
    const int* dst = edge_index + E;

    // workspace layout (~82 MB)
    char* ws = (char*)d_ws;
    size_t off = 0;
    unsigned short* hbf   = (unsigned short*)(ws + off); off += (size_t)M * HID * 2;    // 12.8MB
    unsigned short* aggbf = (unsigned short*)(ws + off); off += (size_t)M * HID * 2;    // 12.8MB
    unsigned short* S     = (unsigned short*)(ws + off); off += (size_t)M * 512 * 2;    // 51.2MB
    unsigned short* Wcat  = (unsigned short*)(ws + off); off += (size_t)128 * 512 * 2;  // 128KB
    unsigned short* Wgru  = (unsigned short*)(ws + off); off += (size_t)512 * 256 * 2;  // 256KB
    float*          cnt4  = (float*)(ws + off);          off += (size_t)M * 4 * 4;      // 800KB
    int* deg      = (int*)(ws + off); off += (size_t)M * 4;
    int* rowptr   = (int*)(ws + off); off += (size_t)M * 4;
    int* cursor   = (int*)(ws + off); off += (size_t)M * 4;
    int* blocksum = (int*)(ws + off); off += 256 * 4;
    int* blockoff = (int*)(ws + off); off += 256 * 4;
    int* csr      = (int*)(ws + off); off += (size_t)E * 4;

    const int total4 = M * HID / 4;
    const int nb_cvt = (total4 + 255) / 256;     // 6250
    const int nb_zero = (M + 255) / 256;         // 196
    const int nb = (M + 255) / 256;              // 196 <= 256

    prep_kernel<<<nb_cvt + 768 + nb_zero, 256, 0, stream>>>(
        node_states, hbf, edge_W, Wcat, w_ih, w_hh, Wgru, deg, total4, nb_cvt, M);

    hist_kernel<<<(E + 255) / 256, 256, 0, stream>>>(dst, deg, E);
    scan_blocks_kernel<<<nb, 256, 0, stream>>>(deg, rowptr, blocksum, M);
    scan_top_kernel<<<1, 256, 0, stream>>>(blocksum, blockoff, nb);
    finalize_kernel<<<(M + 255) / 256, 256, 0, stream>>>(rowptr, blockoff, cursor, M);
    fill_kernel<<<(E + 255) / 256, 256, 0, stream>>>(src, dst, edge_type, cursor, csr, E);

    gather_s_kernel<<<(M + 3) / 4, 256, 0, stream>>>(rowptr, deg, csr, (const uint2*)hbf,
                                                     (float4*)cnt4, (uint2*)S, M);

    agg_gemm<<<(M + 127) / 128, 256, 0, stream>>>(S, Wcat, (const float4*)cnt4, edge_b, aggbf, M);

    dim3 ggrid((M + 63) / 64, 2);
    gemm_gru<<<ggrid, 256, 0, stream>>>(Wgru, aggbf, hbf, b_ih, b_hh, (float*)d_out, M);
}

// Round 9
// 286.461 us; speedup vs baseline: 1.4651x; 1.0879x over previous
//
#include <hip/hip_runtime.h>

// ---------------------------------------------------------------------------
// GGNN message passing, MI355X/gfx950.  Round 9:
//   - (dst,type)-segmented CSR (R6's verified build) + SNAPSHOT GATHER:
//     walk the node's edge list in type order with ONE running accumulator
//     (pure adds, ~5 VALU/edge vs R8's 32-op select ladder, VALUBusy 47%),
//     snapshot at the 3 segment boundaries, typed sums = differences.
//     Counts = rowptr4 diffs (per-edge cpack deleted).
//   - agg_gemm reverted to R5 in-loop weight frags (R8 hoist held 64 VGPRs
//     across the barrier; suspected cause of the +12us regression).
//   - gemm_gru kept from R8 (grid.y=2 gate halves, h blended from the staged
//     hbf LDS tile, LDS-staged coalesced out stores).
// Lessons kept: no gather-into-GEMM fusion (R6: serializes); no K-merging
// (R7: GEMM time scales with K); LDS-staged epilogue stores (R5).
// ---------------------------------------------------------------------------

typedef __attribute__((ext_vector_type(8))) short short8;
typedef __attribute__((ext_vector_type(4))) float floatx4;

#define HID 128
#define NTY 4

__device__ __forceinline__ unsigned short f2bf(float f) {
    unsigned int u = __float_as_uint(f);
    unsigned int r = (u + 0x7fffu + ((u >> 16) & 1u)) >> 16;  // RNE
    return (unsigned short)r;
}
__device__ __forceinline__ float bf2f(unsigned int lo16) {
    return __uint_as_float(lo16 << 16);
}

// ---- prep: cvt_h | pack_wcat | pack_wgru | zero deg4, one dispatch --------

__global__ void prep_kernel(const float* __restrict__ h, unsigned short* __restrict__ hbf,
                            const float* __restrict__ W, unsigned short* __restrict__ Wc,
                            const float* __restrict__ w_ih, const float* __restrict__ w_hh,
                            unsigned short* __restrict__ Wg, int* __restrict__ deg4,
                            int total4, int nb_cvt, int N4) {
    int b = blockIdx.x, tt = threadIdx.x;
    if (b < nb_cvt) {
        int i = b * 256 + tt;
        if (i < total4) {
            float4 v = ((const float4*)h)[i];
            uint2 o;
            o.x = (unsigned int)f2bf(v.x) | ((unsigned int)f2bf(v.y) << 16);
            o.y = (unsigned int)f2bf(v.z) | ((unsigned int)f2bf(v.w) << 16);
            ((uint2*)hbf)[i] = o;
        }
    } else if (b < nb_cvt + 256) {
        // Wcat[j][t*128+k] = edge_W[t][j][k]  (128 x 512)
        int idx = (b - nb_cvt) * 256 + tt;
        int j = idx >> 9, rem = idx & 511;
        int t = rem >> 7, k = rem & 127;
        Wc[idx] = f2bf(W[(t * HID + j) * HID + k]);
    } else if (b < nb_cvt + 768) {
        // Wg[512][256]: rows 4j+{0,1,2,3} = r|z|i_n|h_n
        int idx = (b - nb_cvt - 256) * 256 + tt;
        int row = idx >> 8, k = idx & 255;
        int j = row >> 2, g = row & 3;
        float v = 0.0f;
        if (g == 0) v = (k < 128) ? w_ih[j * 128 + k]         : w_hh[j * 128 + (k - 128)];
        else if (g == 1) v = (k < 128) ? w_ih[(128 + j) * 128 + k] : w_hh[(128 + j) * 128 + (k - 128)];
        else if (g == 2) v = (k < 128) ? w_ih[(256 + j) * 128 + k] : 0.0f;
        else             v = (k < 128) ? 0.0f : w_hh[(256 + j) * 128 + (k - 128)];
        Wg[idx] = f2bf(v);
    } else {
        int i = (b - nb_cvt - 768) * 256 + tt;
        if (i < N4) deg4[i] = 0;
    }
}

// ---- (dst,type)-segmented CSR construction (R6, verified) -----------------

__global__ void hist4_kernel(const int* __restrict__ dst, const int* __restrict__ ety,
                             int* __restrict__ deg4, int E) {
    int e = blockIdx.x * blockDim.x + threadIdx.x;
    if (e < E) atomicAdd(&deg4[dst[e] * 4 + ety[e]], 1);
}

// 1024 elements per block (4 per thread) exclusive scan
__global__ void scan_blocks4_kernel(const int* __restrict__ deg, int* __restrict__ rowptr,
                                    int* __restrict__ blocksum, int N4) {
    __shared__ int s[256];
    int t = threadIdx.x;
    int base = blockIdx.x * 1024 + t * 4;
    int v0 = 0, v1 = 0, v2 = 0, v3 = 0;
    if (base + 3 < N4) {
        v0 = deg[base]; v1 = deg[base + 1]; v2 = deg[base + 2]; v3 = deg[base + 3];
    } else {
        if (base < N4) v0 = deg[base];
        if (base + 1 < N4) v1 = deg[base + 1];
        if (base + 2 < N4) v2 = deg[base + 2];
    }
    int sum = v0 + v1 + v2 + v3;
    s[t] = sum;
    __syncthreads();
#pragma unroll
    for (int off = 1; off < 256; off <<= 1) {
        int x = (t >= off) ? s[t - off] : 0;
        __syncthreads();
        s[t] += x;
        __syncthreads();
    }
    int ex = s[t] - sum;
    if (base < N4) rowptr[base] = ex;
    if (base + 1 < N4) rowptr[base + 1] = ex + v0;
    if (base + 2 < N4) rowptr[base + 2] = ex + v0 + v1;
    if (base + 3 < N4) rowptr[base + 3] = ex + v0 + v1 + v2;
    if (t == 255) blocksum[blockIdx.x] = s[255];
}

__global__ void scan_top_kernel(const int* __restrict__ blocksum, int* __restrict__ blockoff, int nb) {
    __shared__ int s[256];
    int t = threadIdx.x;
    int v = (t < nb) ? blocksum[t] : 0;
    s[t] = v;
    __syncthreads();
#pragma unroll
    for (int off = 1; off < 256; off <<= 1) {
        int x = (t >= off) ? s[t - off] : 0;
        __syncthreads();
        s[t] += x;
        __syncthreads();
    }
    if (t < nb) blockoff[t] = s[t] - v;
}

__global__ void finalize4_kernel(int* __restrict__ rowptr, const int* __restrict__ blockoff,
                                 int* __restrict__ cursor, int N4, int E) {
    int i = blockIdx.x * blockDim.x + threadIdx.x;
    if (i >= N4) return;
    int r = rowptr[i] + blockoff[i >> 10];
    rowptr[i] = r;
    cursor[i] = r;
    if (i == 0) rowptr[N4] = E;  // sentinel
}

__global__ void fill4_kernel(const int* __restrict__ src, const int* __restrict__ dst,
                             const int* __restrict__ ety, int* __restrict__ cursor,
                             int* __restrict__ csr, int E) {
    int e = blockIdx.x * blockDim.x + threadIdx.x;
    if (e >= E) return;
    int pos = atomicAdd(&cursor[dst[e] * 4 + ety[e]], 1);
    csr[pos] = src[e];  // plain src; type implied by segment
}

// ---- gather_s v3: snapshot gather over the type-sorted edge list ----------
// One wave per node; lane owns cols {2l,2l+1} (one uint).  Single running
// accumulator, pure adds; snapshot at segment boundaries; typed sums by
// difference.  Counts = rowptr4 diffs.

__global__ void gather_s_kernel(const int* __restrict__ rowptr4, const int* __restrict__ csr,
                                const unsigned int* __restrict__ hbu,
                                float4* __restrict__ cnt4, unsigned int* __restrict__ Su, int N) {
    int w = blockIdx.x * (blockDim.x >> 6) + (threadIdx.x >> 6);
    if (w >= N) return;
    int lane = threadIdx.x & 63;
    int b0 = rowptr4[w * 4];
    int b1 = rowptr4[w * 4 + 1];
    int b2 = rowptr4[w * 4 + 2];
    int b3 = rowptr4[w * 4 + 3];
    int b4 = rowptr4[w * 4 + 4];  // sentinel-backed for w = N-1

    float s0 = 0.f, s1 = 0.f;
    float sn0[4], sn1[4];
    int e = b0;
#pragma unroll
    for (int t = 0; t < 4; ++t) {
        int bend = (t == 0) ? b1 : (t == 1) ? b2 : (t == 2) ? b3 : b4;
        for (; e + 8 <= bend; e += 8) {
            int p[8];
            unsigned int u[8];
#pragma unroll
            for (int i = 0; i < 8; ++i) p[i] = csr[e + i];
#pragma unroll
            for (int i = 0; i < 8; ++i) u[i] = hbu[(size_t)p[i] * 64 + lane];
#pragma unroll
            for (int i = 0; i < 8; ++i) {
                s0 += bf2f(u[i] & 0xffffu);
                s1 += bf2f(u[i] >> 16);
            }
        }
        for (; e + 4 <= bend; e += 4) {
            int p[4];
            unsigned int u[4];
#pragma unroll
            for (int i = 0; i < 4; ++i) p[i] = csr[e + i];
#pragma unroll
            for (int i = 0; i < 4; ++i) u[i] = hbu[(size_t)p[i] * 64 + lane];
#pragma unroll
            for (int i = 0; i < 4; ++i) {
                s0 += bf2f(u[i] & 0xffffu);
                s1 += bf2f(u[i] >> 16);
            }
        }
        for (; e < bend; ++e) {
            unsigned int u = hbu[(size_t)csr[e] * 64 + lane];
            s0 += bf2f(u & 0xffffu);
            s1 += bf2f(u >> 16);
        }
        sn0[t] = s0;
        sn1[t] = s1;
    }
    // typed sums by difference; write S rows (coalesced 256B per type)
    float p0 = 0.f, p1 = 0.f;
    size_t base = (size_t)w * 256 + lane;
#pragma unroll
    for (int t = 0; t < 4; ++t) {
        float a0 = sn0[t] - p0, a1 = sn1[t] - p1;
        p0 = sn0[t]; p1 = sn1[t];
        Su[base + t * 64] = (unsigned int)f2bf(a0) | ((unsigned int)f2bf(a1) << 16);
    }
    if (lane == 0)
        cnt4[w] = make_float4((float)(b1 - b0), (float)(b2 - b1),
                              (float)(b3 - b2), (float)(b4 - b3));
}

// ---- agg_gemm (R5): aggbf[M x 128] = S[M x 512] @ Wcat[128 x 512]^T + bias
// 128-node tile, in-loop weight frags, LDS-staged coalesced store.

__global__ __launch_bounds__(256) void agg_gemm(const unsigned short* __restrict__ S,
                                                const unsigned short* __restrict__ Wc,
                                                const float4* __restrict__ cnt4,
                                                const float* __restrict__ eb,
                                                unsigned short* __restrict__ aggbf, int M) {
    __shared__ __align__(16) unsigned short Ss[128][136];
    const int tid = threadIdx.x;
    const int m0 = blockIdx.x * 128;
    const int lane = tid & 63, wave = tid >> 6;
    const int wm = wave >> 1, wn = wave & 1;
    const int lm = lane & 15, quad = lane >> 4;

    floatx4 acc[4][4];
#pragma unroll
    for (int a = 0; a < 4; ++a)
#pragma unroll
        for (int b = 0; b < 4; ++b) acc[a][b] = (floatx4){0.f, 0.f, 0.f, 0.f};

    for (int c = 0; c < 4; ++c) {  // K = 512, BK = 128
        {
            int rr = tid >> 4;
            int cc = (tid & 15) * 8;
#pragma unroll
            for (int p = 0; p < 8; ++p) {
                int r = rr + p * 16;
                int gm = m0 + r;
                uint4 v = {0u, 0u, 0u, 0u};
                if (gm < M) v = *(const uint4*)(S + (size_t)gm * 512 + c * 128 + cc);
                *(uint4*)&Ss[r][cc] = v;
            }
        }
        __syncthreads();
#pragma unroll
        for (int s = 0; s < 4; ++s) {
            short8 af[4], bfr[4];
#pragma unroll
            for (int mi = 0; mi < 4; ++mi)
                af[mi] = *(const short8*)&Ss[wm * 64 + mi * 16 + lm][s * 32 + quad * 8];
#pragma unroll
            for (int ni = 0; ni < 4; ++ni) {
                int j = wn * 64 + ni * 16 + lm;
                bfr[ni] = *(const short8*)(Wc + (size_t)j * 512 + c * 128 + s * 32 + quad * 8);
            }
#pragma unroll
            for (int mi = 0; mi < 4; ++mi)
#pragma unroll
                for (int ni = 0; ni < 4; ++ni)
                    acc[mi][ni] = __builtin_amdgcn_mfma_f32_16x16x32_bf16(af[mi], bfr[ni], acc[mi][ni], 0, 0, 0);
        }
        __syncthreads();
    }
    // epilogue: stage bf16 results into Ss, coalesced write
#pragma unroll
    for (int mi = 0; mi < 4; ++mi) {
        int row_b = wm * 64 + mi * 16 + quad * 4;
#pragma unroll
        for (int r = 0; r < 4; ++r) {
            int lrow = row_b + r;
            int node = m0 + lrow;
            float4 c4 = (node < M) ? cnt4[node] : make_float4(0.f, 0.f, 0.f, 0.f);
#pragma unroll
            for (int ni = 0; ni < 4; ++ni) {
                int j = wn * 64 + ni * 16 + lm;
                float v = acc[mi][ni][r];
                v += c4.x * eb[j] + c4.y * eb[HID + j] + c4.z * eb[2 * HID + j] + c4.w * eb[3 * HID + j];
                Ss[lrow][j] = f2bf(v);
            }
        }
    }
    __syncthreads();
    {
        int row = tid >> 1;              // 0..127
        int halfc = (tid & 1) * 64;      // shorts
        int node = m0 + row;
        if (node < M) {
#pragma unroll
            for (int i = 0; i < 8; ++i)
                *(uint4*)(aggbf + (size_t)node * HID + halfc + i * 8) = *(const uint4*)&Ss[row][halfc + i * 8];
        }
    }
}

// ---- gemm_gru (R8): C'[512 x M] = Wg @ [aggbf|hbf]^T ----------------------
// grid.y = gate-half; 64-node tiles; wave w owns 64 gate rows x 64 nodes.
// acc[mi][ni][0..3] = (r,z,i_n,h_n) of (node, j).  h blended from the hbf
// Xs tile (staged last).  Out via fp32 LDS tile, coalesced float4 stores.

__global__ __launch_bounds__(256) void gemm_gru(const unsigned short* __restrict__ Wg,
                                                const unsigned short* __restrict__ aggbf,
                                                const unsigned short* __restrict__ hbf,
                                                const float* __restrict__ b_ih,
                                                const float* __restrict__ b_hh,
                                                float* __restrict__ out, int M) {
    __shared__ __align__(16) unsigned short Xs[64][136];
    __shared__ __align__(16) float Outs[64][68];
    const int tid = threadIdx.x;
    const int n0 = blockIdx.x * 64;       // node tile
    const int gh = blockIdx.y;            // gate half: rows [gh*256, gh*256+256)
    const int lane = tid & 63, w = tid >> 6;
    const int lm = lane & 15, quad = lane >> 4;

    floatx4 acc[4][4];
#pragma unroll
    for (int a = 0; a < 4; ++a)
#pragma unroll
        for (int b = 0; b < 4; ++b) acc[a][b] = (floatx4){0.f, 0.f, 0.f, 0.f};

    for (int c = 0; c < 2; ++c) {
        const unsigned short* Xp = c ? hbf : aggbf;  // hbf last -> Xs = hbf at epilogue
        {
            int rr = tid >> 4;         // 0..15
            int cc = (tid & 15) * 8;   // 0..120
#pragma unroll
            for (int p = 0; p < 4; ++p) {
                int r = rr + p * 16;   // 0..63
                int gn = n0 + r;
                uint4 v = {0u, 0u, 0u, 0u};
                if (gn < M) v = *(const uint4*)(Xp + (size_t)gn * HID + cc);
                *(uint4*)&Xs[r][cc] = v;
            }
        }
        __syncthreads();
#pragma unroll
        for (int s = 0; s < 4; ++s) {
            short8 bfr[4];
#pragma unroll
            for (int ni = 0; ni < 4; ++ni)
                bfr[ni] = *(const short8*)&Xs[ni * 16 + lm][s * 32 + quad * 8];
            short8 af[4];
#pragma unroll
            for (int mi = 0; mi < 4; ++mi) {
                int rowg = gh * 256 + w * 64 + mi * 16 + lm;
                af[mi] = *(const short8*)(Wg + (size_t)rowg * 256 + c * 128 + s * 32 + quad * 8);
            }
#pragma unroll
            for (int mi = 0; mi < 4; ++mi)
#pragma unroll
                for (int ni = 0; ni < 4; ++ni)
                    acc[mi][ni] = __builtin_amdgcn_mfma_f32_16x16x32_bf16(af[mi], bfr[ni], acc[mi][ni], 0, 0, 0);
        }
        __syncthreads();  // protect restage; after c=1, Xs stays = hbf
    }

    // epilogue: gate row = gh*256 + w*64 + mi*16 + quad*4 + g -> j = row>>2
#pragma unroll
    for (int mi = 0; mi < 4; ++mi) {
        int jl = w * 16 + mi * 4 + quad;  // 0..63 within half
        int j = gh * 64 + jl;             // 0..127
        float brj = b_ih[j] + b_hh[j];
        float bzj = b_ih[128 + j] + b_hh[128 + j];
        float bin = b_ih[256 + j];
        float bhn = b_hh[256 + j];
#pragma unroll
        for (int ni = 0; ni < 4; ++ni) {
            int lrow = ni * 16 + lm;
            float g0 = acc[mi][ni][0], g1 = acc[mi][ni][1];
            float g2 = acc[mi][ni][2], g3 = acc[mi][ni][3];
            float r = 1.0f / (1.0f + __expf(-(g0 + brj)));
            float z = 1.0f / (1.0f + __expf(-(g1 + bzj)));
            float nn = tanhf(g2 + bin + r * (g3 + bhn));
            float hv = bf2f((unsigned int)Xs[lrow][j]);  // hbf tile
            Outs[lrow][jl] = (1.0f - z) * nn + z * hv;
        }
    }
    __syncthreads();
    // coalesced write: 64 nodes x 64 floats (256B contiguous per node)
    {
        int row = tid >> 2;              // 0..63
        int c0 = (tid & 3) * 16;         // 0..48
        int node = n0 + row;
        if (node < M) {
            float* dstp = out + (size_t)node * HID + gh * 64 + c0;
#pragma unroll
            for (int i = 0; i < 4; ++i)
                *(float4*)(dstp + i * 4) = *(const float4*)&Outs[row][c0 + i * 4];
        }
    }
}

// ---------------------------------------------------------------------------

extern "C" void kernel_launch(void* const* d_in, const int* in_sizes, int n_in,
                              void* d_out, int out_size, void* d_ws, size_t ws_size,
                              hipStream_t stream) {
    const float* node_states = (const float*)d_in[0];
    const int*   edge_index  = (const int*)d_in[1];
    const int*   edge_type   = (const int*)d_in[2];
    const float* edge_W      = (const float*)d_in[3];
    const float* edge_b      = (const float*)d_in[4];
    const float* w_ih        = (const float*)d_in[5];
    const float* w_hh        = (const float*)d_in[6];
    const float* b_ih        = (const float*)d_in[7];
    const float* b_hh        = (const float*)d_in[8];

    const int M = in_sizes[0] / HID;      // 50000 nodes
    const int E = in_sizes[1] / 2;        // 625000 edges
    const int N4 = M * 4;                 // 200000 (dst,type) segments
    const int* src = edge_index;
    const int* dst = edge_index + E;

    // workspace layout (~84 MB)
    char* ws = (char*)d_ws;
    size_t off = 0;
    unsigned short* hbf   = (unsigned short*)(ws + off); off += (size_t)M * HID * 2;    // 12.8MB
    unsigned short* aggbf = (unsigned short*)(ws + off); off += (size_t)M * HID * 2;    // 12.8MB
    unsigned short* S     = (unsigned short*)(ws + off); off += (size_t)M * 512 * 2;    // 51.2MB
    unsigned short* Wcat  = (unsigned short*)(ws + off); off += (size_t)128 * 512 * 2;  // 128KB
    unsigned short* Wgru  = (unsigned short*)(ws + off); off += (size_t)512 * 256 * 2;  // 256KB
    float*          cnt4  = (float*)(ws + off);          off += (size_t)M * 4 * 4;      // 800KB
    int* deg4     = (int*)(ws + off); off += (size_t)N4 * 4;
    int* rowptr4  = (int*)(ws + off); off += (size_t)(N4 + 1) * 4;
    int* cursor4  = (int*)(ws + off); off += (size_t)N4 * 4;
    int* blocksum = (int*)(ws + off); off += 256 * 4;
    int* blockoff = (int*)(ws + off); off += 256 * 4;
    int* csr      = (int*)(ws + off); off += (size_t)E * 4;

    const int total4 = M * HID / 4;
    const int nb_cvt = (total4 + 255) / 256;     // 6250
    const int nb_zero = (N4 + 255) / 256;        // 782
    const int nb_scan = (N4 + 1023) / 1024;      // 196 <= 256

    prep_kernel<<<nb_cvt + 768 + nb_zero, 256, 0, stream>>>(
        node_states, hbf, edge_W, Wcat, w_ih, w_hh, Wgru, deg4, total4, nb_cvt, N4);

    hist4_kernel<<<(E + 255) / 256, 256, 0, stream>>>(dst, edge_type, deg4, E);
    scan_blocks4_kernel<<<nb_scan, 256, 0, stream>>>(deg4, rowptr4, blocksum, N4);
    scan_top_kernel<<<1, 256, 0, stream>>>(blocksum, blockoff, nb_scan);
    finalize4_kernel<<<(N4 + 255) / 256, 256, 0, stream>>>(rowptr4, blockoff, cursor4, N4, E);
    fill4_kernel<<<(E + 255) / 256, 256, 0, stream>>>(src, dst, edge_type, cursor4, csr, E);

    gather_s_kernel<<<(M + 3) / 4, 256, 0, stream>>>(rowptr4, csr, (const unsigned int*)hbf,
                                                     (float4*)cnt4, (unsigned int*)S, M);

    agg_gemm<<<(M + 127) / 128, 256, 0, stream>>>(S, Wcat, (const float4*)cnt4, edge_b, aggbf, M);

    dim3 ggrid((M + 63) / 64, 2);
    gemm_gru<<<ggrid, 256, 0, stream>>>(Wgru, aggbf, hbf, b_ih, b_hh, (float*)d_out, M);
}